// Round 9
// baseline (240.011 us; speedup 1.0000x reference)
//
#include <hip/hip_runtime.h>
#include <math.h>

#define BN_EPS 1e-5f
#define NEG_SLOPE 0.2f

typedef __attribute__((ext_vector_type(8))) short bf16x8;
typedef __attribute__((ext_vector_type(4))) float f32x4;

__device__ __forceinline__ float relu_f(float x) { return x > 0.f ? x : 0.f; }
__device__ __forceinline__ float leaky_f(float z) { return z > 0.f ? z : NEG_SLOPE * z; }

__device__ __forceinline__ unsigned short f2b(float f) {
    union { float f; unsigned int i; } u; u.f = f;
    unsigned int r = u.i + 0x7fffu + ((u.i >> 16) & 1u);
    return (unsigned short)(r >> 16);
}
__device__ __forceinline__ float b2f(unsigned short v) {
    union { unsigned int i; float f; } u; u.i = ((unsigned int)v) << 16;
    return u.f;
}
__device__ __forceinline__ void split_b(float x, unsigned short& hi, unsigned short& lo) {
    hi = f2b(x);
    lo = f2b(x - b2f(hi));
}

// ---------------- conv1 (R5 verbatim): 3->64 + bias+BN+ReLU + 2x2maxpool, NCHW fp32 out ----------------
__global__ void conv1_pool(const float* __restrict__ img, const float* __restrict__ w,
                           const float* __restrict__ cb, const float* __restrict__ g,
                           const float* __restrict__ bb, const float* __restrict__ m,
                           const float* __restrict__ vv, float* __restrict__ out)
{
    int blk = blockIdx.x;
    int q = blk & 3, cog = (blk >> 2) & 15, b = blk >> 6;
    int t = threadIdx.x;
    int x = t & 31, y = (q << 3) + (t >> 5);

    float acc[4][4] = {};
#pragma unroll
    for (int ci = 0; ci < 3; ++ci) {
        const float* ib = img + (b * 3 + ci) * 4096;
        float rv[4][4];
#pragma unroll
        for (int r = 0; r < 4; ++r) {
            int yy = 2 * y - 1 + r;
            bool yok = (unsigned)yy < 64u;
            const float* p = ib + yy * 64 + 2 * x;
            float2 c01 = yok ? *(const float2*)p : make_float2(0.f, 0.f);
            rv[r][1] = c01.x;
            rv[r][2] = c01.y;
            rv[r][0] = (yok && x > 0) ? p[-1] : 0.f;
            rv[r][3] = (yok && x < 31) ? p[2] : 0.f;
        }
#pragma unroll
        for (int j = 0; j < 4; ++j) {
            const float* wj = w + ((cog * 4 + j) * 3 + ci) * 9;
#pragma unroll
            for (int ky = 0; ky < 3; ++ky)
#pragma unroll
                for (int kx = 0; kx < 3; ++kx) {
                    float wvv = wj[ky * 3 + kx];
#pragma unroll
                    for (int py = 0; py < 2; ++py)
#pragma unroll
                        for (int px = 0; px < 2; ++px)
                            acc[j][py * 2 + px] += rv[py + ky][px + kx] * wvv;
                }
        }
    }
#pragma unroll
    for (int j = 0; j < 4; ++j) {
        int co = cog * 4 + j;
        float inv = g[co] / sqrtf(vv[co] + BN_EPS);
        float sh = cb[co] * inv + (bb[co] - m[co] * inv);
        float v0 = relu_f(acc[j][0] * inv + sh);
        float v1 = relu_f(acc[j][1] * inv + sh);
        float v2 = relu_f(acc[j][2] * inv + sh);
        float v3 = relu_f(acc[j][3] * inv + sh);
        out[((b * 64 + co) * 32 + y) * 32 + x] = fmaxf(fmaxf(v0, v1), fmaxf(v2, v3));
    }
}

// ---------------- conv2 (R5 verbatim): 64->128, fp32, 2 x-pos x 4 co per thread ----------------
__global__ void conv2_fused(const float* __restrict__ in, const float* __restrict__ w,
                            const float* __restrict__ cb, const float* __restrict__ g,
                            const float* __restrict__ bb, const float* __restrict__ m,
                            const float* __restrict__ vv, float* __restrict__ x0)
{
    int blk = blockIdx.x;
    int half = blk & 1, cog = (blk >> 1) & 31, b = blk >> 6;
    int t = threadIdx.x;
    int x2p = (t & 15) * 2;
    int y = half * 16 + (t >> 4);
    bool xnz = x2p != 0;
    bool xhi = x2p == 30;
    const float* ibase = in + b * 64 * 1024;
    int xb = xnz ? x2p - 1 : 0;

    float acc[4][2] = {};

#pragma unroll 2
    for (int ci = 0; ci < 64; ++ci) {
        const float* cb2 = ibase + ci * 1024;
        float rc[3][4];
#pragma unroll
        for (int r = 0; r < 3; ++r) {
            int yy = y - 1 + r;
            bool yok = (unsigned)yy < 32u;
            const float* p = cb2 + yy * 32 + xb;
            float4 f = yok ? *(const float4*)p : make_float4(0.f, 0.f, 0.f, 0.f);
            rc[r][0] = xnz ? f.x : 0.f;
            rc[r][1] = xnz ? f.y : f.x;
            rc[r][2] = xnz ? f.z : f.y;
            float r3 = xnz ? f.w : f.z;
            rc[r][3] = xhi ? 0.f : r3;
        }
#pragma unroll
        for (int j = 0; j < 4; ++j) {
            const float* wj = w + ((cog * 4 + j) * 64 + ci) * 9;
#pragma unroll
            for (int ky = 0; ky < 3; ++ky)
#pragma unroll
                for (int kx = 0; kx < 3; ++kx) {
                    float wvv = wj[ky * 3 + kx];
                    acc[j][0] += rc[ky][kx] * wvv;
                    acc[j][1] += rc[ky][kx + 1] * wvv;
                }
        }
    }

    float o0[4], o1[4];
#pragma unroll
    for (int j = 0; j < 4; ++j) {
        int co = cog * 4 + j;
        float inv = g[co] / sqrtf(vv[co] + BN_EPS);
        float sh = cb[co] * inv + (bb[co] - m[co] * inv);
        o0[j] = relu_f(acc[j][0] * inv + sh);
        o1[j] = relu_f(acc[j][1] * inv + sh);
    }
    int n0 = b * 1024 + y * 32 + x2p;
    float4 s0 = {o0[0], o0[1], o0[2], o0[3]};
    float4 s1 = {o1[0], o1[1], o1[2], o1[3]};
    *(float4*)&x0[(size_t)n0 * 128 + cog * 4] = s0;
    *(float4*)&x0[(size_t)(n0 + 1) * 128 + cog * 4] = s1;
}

// ---------------- weight prep (hi/lo): W1T[n][k] (256x128), W2T[n][k] (128x256) ----------------
__global__ void wprep_w(const float* __restrict__ W1, const float* __restrict__ W2,
                        unsigned short* __restrict__ W1H, unsigned short* __restrict__ W1L,
                        unsigned short* __restrict__ W2H, unsigned short* __restrict__ W2L)
{
    int idx = blockIdx.x * 256 + threadIdx.x;
    if (idx < 32768) {
        int k = idx & 127, n = idx >> 7;
        split_b(W1[k * 256 + n], W1H[idx], W1L[idx]);
    } else {
        int i = idx - 32768;
        int k = i & 255, n = i >> 8;
        split_b(W2[k * 128 + n], W2H[i], W2L[i]);
    }
}

// ---------------- split x0 fp32 -> hi/lo bf16 planes ----------------
__global__ void xprep(const float* __restrict__ x0, unsigned short* __restrict__ xH,
                      unsigned short* __restrict__ xL)
{
    int idx = blockIdx.x * 256 + threadIdx.x;   // over 1048576/4
    float4 v = ((const float4*)x0)[idx];
    ushort4 h, l;
    split_b(v.x, h.x, l.x);
    split_b(v.y, h.y, l.y);
    split_b(v.z, h.z, l.z);
    split_b(v.w, h.w, l.w);
    ((ushort4*)xH)[idx] = h;
    ((ushort4*)xL)[idx] = l;
}

// ---------------- MFMA GEMM (hi/lo): C fp32 [M][NN] = A @ BT^T; CT hi/lo [NN][1024] rows<1024 ----------------
template <int K, int NN, int WRITE_T>
__global__ void gemm_mfma(const unsigned short* __restrict__ AH, const unsigned short* __restrict__ AL,
                          const unsigned short* __restrict__ BH, const unsigned short* __restrict__ BL,
                          float* __restrict__ C, unsigned short* __restrict__ CTH,
                          unsigned short* __restrict__ CTL)
{
    __shared__ short AsH[64][40], AsL[64][40];
    __shared__ short BsH[64][40], BsL[64][40];
    int t = threadIdx.x, w = t >> 6, l = t & 63;
    int m0 = blockIdx.x * 64, n0 = blockIdx.y * 64;
    int sm = t >> 2, sk8 = (t & 3) * 8;
    f32x4 acc[4] = {};
    for (int k0 = 0; k0 < K; k0 += 32) {
        size_t ao = (size_t)(m0 + sm) * K + k0 + sk8;
        size_t bo = (size_t)(n0 + sm) * K + k0 + sk8;
        uint4 avh = *(const uint4*)&AH[ao];
        uint4 avl = *(const uint4*)&AL[ao];
        uint4 bvh = *(const uint4*)&BH[bo];
        uint4 bvl = *(const uint4*)&BL[bo];
        __syncthreads();
        *(uint4*)&AsH[sm][sk8] = avh;
        *(uint4*)&AsL[sm][sk8] = avl;
        *(uint4*)&BsH[sm][sk8] = bvh;
        *(uint4*)&BsL[sm][sk8] = bvl;
        __syncthreads();
        int ar = w * 16 + (l & 15), akk = (l >> 4) * 8;
        bf16x8 afh = *(const bf16x8*)&AsH[ar][akk];
        bf16x8 afl = *(const bf16x8*)&AsL[ar][akk];
#pragma unroll
        for (int nt = 0; nt < 4; ++nt) {
            int br = nt * 16 + (l & 15);
            bf16x8 bh = *(const bf16x8*)&BsH[br][akk];
            bf16x8 bl = *(const bf16x8*)&BsL[br][akk];
            acc[nt] = __builtin_amdgcn_mfma_f32_16x16x32_bf16(afh, bh, acc[nt], 0, 0, 0);
            acc[nt] = __builtin_amdgcn_mfma_f32_16x16x32_bf16(afh, bl, acc[nt], 0, 0, 0);
            acc[nt] = __builtin_amdgcn_mfma_f32_16x16x32_bf16(afl, bh, acc[nt], 0, 0, 0);
        }
    }
    int rb = m0 + w * 16 + (l >> 4) * 4;
#pragma unroll
    for (int nt = 0; nt < 4; ++nt) {
        int col = n0 + nt * 16 + (l & 15);
        C[(size_t)(rb + 0) * NN + col] = acc[nt][0];
        C[(size_t)(rb + 1) * NN + col] = acc[nt][1];
        C[(size_t)(rb + 2) * NN + col] = acc[nt][2];
        C[(size_t)(rb + 3) * NN + col] = acc[nt][3];
        if (WRITE_T && rb < 1024) {
            ushort4 ch, cl;
            unsigned short hh, ll;
            split_b(acc[nt][0], hh, ll); ch.x = hh; cl.x = ll;
            split_b(acc[nt][1], hh, ll); ch.y = hh; cl.y = ll;
            split_b(acc[nt][2], hh, ll); ch.z = hh; cl.z = ll;
            split_b(acc[nt][3], hh, ll); ch.w = hh; cl.w = ll;
            *(ushort4*)&CTH[(size_t)col * 1024 + rb] = ch;
            *(ushort4*)&CTL[(size_t)col * 1024 + rb] = cl;
        }
    }
}

// ---------------- attention scores for rows < 1024 (one wave per row), h fp32 ----------------
__global__ void score_kernel(const float* __restrict__ h, const float* __restrict__ asrc,
                             const float* __restrict__ adst, float* __restrict__ s,
                             float* __restrict__ d, int D)
{
    int gt = blockIdx.x * blockDim.x + threadIdx.x;
    int row = gt >> 6, lane = gt & 63;
    const float* hp = h + (size_t)row * D;
    float ss = 0.f, dd = 0.f;
    for (int c0 = lane * 4; c0 < D; c0 += 256) {
        float4 hv = *(const float4*)&hp[c0];
        float4 a4 = *(const float4*)&asrc[c0];
        float4 d4 = *(const float4*)&adst[c0];
        ss += hv.x * a4.x + hv.y * a4.y + hv.z * a4.z + hv.w * a4.w;
        dd += hv.x * d4.x + hv.y * d4.y + hv.z * d4.z + hv.w * d4.w;
    }
    for (int off = 32; off; off >>= 1) {
        ss += __shfl_down(ss, off);
        dd += __shfl_down(dd, off);
    }
    if (lane == 0) { s[row] = ss; d[row] = dd; }
}

// ---------------- GAT aggregation MFMA (hi/lo alpha & B), split-K=8 ----------------
template <int D>
__global__ void gat_mfma(const unsigned short* __restrict__ hTH, const unsigned short* __restrict__ hTL,
                         const float* __restrict__ s, const float* __restrict__ d,
                         float* __restrict__ pacc, float* __restrict__ pden)
{
    constexpr int NT = D / 64;
    __shared__ float Ss[128];
    __shared__ short AsH[32][40], AsL[32][40];
    __shared__ short BsH[D][40], BsL[D][40];
    __shared__ float red[8][32];
    __shared__ float red2[4];
    int t = threadIdx.x, w = t >> 6, l = t & 63;
    int m0 = blockIdx.x * 32;
    int kz = blockIdx.y;
    int ub = kz << 7;

    float4 sv = *(const float4*)&s[t * 4];
    float lm = fmaxf(fmaxf(sv.x, sv.y), fmaxf(sv.z, sv.w));
#pragma unroll
    for (int off = 1; off < 64; off <<= 1) lm = fmaxf(lm, __shfl_xor(lm, off));
    if (l == 0) red2[w] = lm;
    if (t < 128) Ss[t] = s[ub + t];
    __syncthreads();
    float smax = fmaxf(fmaxf(red2[0], red2[1]), fmaxf(red2[2], red2[3]));

    int vv = t & 31, ug = t >> 5;
    float dv = d[m0 + vv];
    float mv = leaky_f(smax + dv);
    float dsum = 0.f;
    f32x4 acc[2][NT] = {};

    for (int st = 0; st < 4; ++st) {
        int u0l = st * 32;
        ushort4 a4h, a4l;
        unsigned short hh, ll;
        float a0 = __expf(leaky_f(Ss[u0l + ug * 4 + 0] + dv) - mv);
        float a1 = __expf(leaky_f(Ss[u0l + ug * 4 + 1] + dv) - mv);
        float a2 = __expf(leaky_f(Ss[u0l + ug * 4 + 2] + dv) - mv);
        float a3 = __expf(leaky_f(Ss[u0l + ug * 4 + 3] + dv) - mv);
        dsum += a0 + a1 + a2 + a3;
        split_b(a0, hh, ll); a4h.x = hh; a4l.x = ll;
        split_b(a1, hh, ll); a4h.y = hh; a4l.y = ll;
        split_b(a2, hh, ll); a4h.z = hh; a4l.z = ll;
        split_b(a3, hh, ll); a4h.w = hh; a4l.w = ll;
        uint4 bvh[NT], bvl[NT];
#pragma unroll
        for (int c = 0; c < NT; ++c) {
            int chunk = c * 256 + t;
            int n = chunk >> 2, kq8 = (chunk & 3) * 8;
            size_t o = (size_t)n * 1024 + ub + u0l + kq8;
            bvh[c] = *(const uint4*)&hTH[o];
            bvl[c] = *(const uint4*)&hTL[o];
        }
        __syncthreads();
        *(ushort4*)&AsH[vv][ug * 4] = a4h;
        *(ushort4*)&AsL[vv][ug * 4] = a4l;
#pragma unroll
        for (int c = 0; c < NT; ++c) {
            int chunk = c * 256 + t;
            int n = chunk >> 2, kq8 = (chunk & 3) * 8;
            *(uint4*)&BsH[n][kq8] = bvh[c];
            *(uint4*)&BsL[n][kq8] = bvl[c];
        }
        __syncthreads();
        int ar = l & 15, akk = (l >> 4) * 8;
        bf16x8 af0h = *(const bf16x8*)&AsH[ar][akk];
        bf16x8 af0l = *(const bf16x8*)&AsL[ar][akk];
        bf16x8 af1h = *(const bf16x8*)&AsH[16 + ar][akk];
        bf16x8 af1l = *(const bf16x8*)&AsL[16 + ar][akk];
#pragma unroll
        for (int nt = 0; nt < NT; ++nt) {
            int br = w * (D / 4) + nt * 16 + ar;
            bf16x8 bh = *(const bf16x8*)&BsH[br][akk];
            bf16x8 bl = *(const bf16x8*)&BsL[br][akk];
            acc[0][nt] = __builtin_amdgcn_mfma_f32_16x16x32_bf16(af0h, bh, acc[0][nt], 0, 0, 0);
            acc[0][nt] = __builtin_amdgcn_mfma_f32_16x16x32_bf16(af0h, bl, acc[0][nt], 0, 0, 0);
            acc[0][nt] = __builtin_amdgcn_mfma_f32_16x16x32_bf16(af0l, bh, acc[0][nt], 0, 0, 0);
            acc[1][nt] = __builtin_amdgcn_mfma_f32_16x16x32_bf16(af1h, bh, acc[1][nt], 0, 0, 0);
            acc[1][nt] = __builtin_amdgcn_mfma_f32_16x16x32_bf16(af1h, bl, acc[1][nt], 0, 0, 0);
            acc[1][nt] = __builtin_amdgcn_mfma_f32_16x16x32_bf16(af1l, bh, acc[1][nt], 0, 0, 0);
        }
    }
    __syncthreads();
    red[ug][vv] = dsum;
    __syncthreads();
    if (t < 32) {
        float dn = 0.f;
#pragma unroll
        for (int i = 0; i < 8; ++i) dn += red[i][t];
        pden[(kz << 10) + m0 + t] = dn;
    }
    int rb = (l >> 4) * 4;
#pragma unroll
    for (int nt = 0; nt < NT; ++nt) {
        int col = w * (D / 4) + nt * 16 + (l & 15);
#pragma unroll
        for (int mt = 0; mt < 2; ++mt)
#pragma unroll
            for (int r = 0; r < 4; ++r) {
                int row = m0 + mt * 16 + rb + r;
                pacc[((size_t)(kz << 10) + row) * D + col] = acc[mt][nt][r];
            }
    }
}

// ---------------- finalize layer1: combine + bias + relu -> x1 hi/lo planes ----------------
template <int D, int KS, int CLOG>
__global__ void gat_fin_hl(const float* __restrict__ pacc, const float* __restrict__ pden,
                           const float* __restrict__ h, const float* __restrict__ bias,
                           unsigned short* __restrict__ outH, unsigned short* __restrict__ outL)
{
    int idx = blockIdx.x * 256 + threadIdx.x;
    int c4 = idx & ((D / 4) - 1);
    int v = idx >> CLOG;
    float4 bz = ((const float4*)bias)[c4];
    float vx, vy, vz, vw;
    if (v < 1024) {
        float ax = 0.f, ay = 0.f, az = 0.f, aw = 0.f, den = 0.f;
#pragma unroll
        for (int ks = 0; ks < KS; ++ks) {
            float4 p = ((const float4*)pacc)[(size_t)((ks << 10) + v) * (D / 4) + c4];
            ax += p.x; ay += p.y; az += p.z; aw += p.w;
            den += pden[(ks << 10) + v];
        }
        float rd = 1.f / den;
        vx = ax * rd; vy = ay * rd; vz = az * rd; vw = aw * rd;
    } else {
        float4 hv = *(const float4*)&h[(size_t)v * D + c4 * 4];
        vx = hv.x; vy = hv.y; vz = hv.z; vw = hv.w;
    }
    ushort4 oh, ol;
    unsigned short hh, ll;
    split_b(relu_f(vx + bz.x), hh, ll); oh.x = hh; ol.x = ll;
    split_b(relu_f(vy + bz.y), hh, ll); oh.y = hh; ol.y = ll;
    split_b(relu_f(vz + bz.z), hh, ll); oh.z = hh; ol.z = ll;
    split_b(relu_f(vw + bz.w), hh, ll); oh.w = hh; ol.w = ll;
    *(ushort4*)&outH[(size_t)v * D + c4 * 4] = oh;
    *(ushort4*)&outL[(size_t)v * D + c4 * 4] = ol;
}

// ---------------- finalize layer2: combine + bias + relu -> x2 fp32 ----------------
template <int D, int KS, int CLOG>
__global__ void gat_fin_f(const float* __restrict__ pacc, const float* __restrict__ pden,
                          const float* __restrict__ h, const float* __restrict__ bias,
                          float* __restrict__ out)
{
    int idx = blockIdx.x * 256 + threadIdx.x;
    int c4 = idx & ((D / 4) - 1);
    int v = idx >> CLOG;
    float4 bz = ((const float4*)bias)[c4];
    float vx, vy, vz, vw;
    if (v < 1024) {
        float ax = 0.f, ay = 0.f, az = 0.f, aw = 0.f, den = 0.f;
#pragma unroll
        for (int ks = 0; ks < KS; ++ks) {
            float4 p = ((const float4*)pacc)[(size_t)((ks << 10) + v) * (D / 4) + c4];
            ax += p.x; ay += p.y; az += p.z; aw += p.w;
            den += pden[(ks << 10) + v];
        }
        float rd = 1.f / den;
        vx = ax * rd; vy = ay * rd; vz = az * rd; vw = aw * rd;
    } else {
        float4 hv = *(const float4*)&h[(size_t)v * D + c4 * 4];
        vx = hv.x; vy = hv.y; vz = hv.z; vw = hv.w;
    }
    float4 o = {relu_f(vx + bz.x), relu_f(vy + bz.y), relu_f(vz + bz.z), relu_f(vw + bz.w)};
    ((float4*)out)[(size_t)v * (D / 4) + c4] = o;
}

// ---------------- mean-pool stage 1 (fp32) ----------------
__global__ void pool_part(const float* __restrict__ x2, float* __restrict__ part)
{
    int b = blockIdx.x >> 4, seg = blockIdx.x & 15, t = threadIdx.x;
    const float* p = x2 + ((size_t)b * 1024 + seg * 64) * 128 + t;
    float acc = 0.f;
#pragma unroll 8
    for (int n = 0; n < 64; ++n) acc += p[(size_t)n * 128];
    part[(b * 16 + seg) * 128 + t] = acc;
}

// ---------------- head: reduce partials + linear + log_softmax ----------------
__global__ void head_kernel(const float* __restrict__ part, const float* __restrict__ ow,
                            const float* __restrict__ ob, float* __restrict__ out)
{
    __shared__ float pooled[128];
    __shared__ float logits[10];
    int b = blockIdx.x, t = threadIdx.x;
    float acc = 0.f;
#pragma unroll
    for (int sgi = 0; sgi < 16; ++sgi) acc += part[(b * 16 + sgi) * 128 + t];
    pooled[t] = acc * (1.f / 1024.f);
    __syncthreads();
    if (t < 10) {
        float l = ob[t];
        for (int c = 0; c < 128; ++c) l += pooled[c] * ow[c * 10 + t];
        logits[t] = l;
    }
    __syncthreads();
    if (t == 0) {
        float mx = logits[0];
        for (int j = 1; j < 10; ++j) mx = fmaxf(mx, logits[j]);
        float sum = 0.f;
        for (int j = 0; j < 10; ++j) sum += expf(logits[j] - mx);
        float lse = mx + logf(sum);
        for (int j = 0; j < 10; ++j) out[b * 10 + j] = logits[j] - lse;
    }
}

extern "C" void kernel_launch(void* const* d_in, const int* in_sizes, int n_in,
                              void* d_out, int out_size, void* d_ws, size_t ws_size,
                              hipStream_t stream)
{
    const float* images = (const float*)d_in[0];
    const float* c1w = (const float*)d_in[1];
    const float* c1b = (const float*)d_in[2];
    const float* bn1g = (const float*)d_in[3];
    const float* bn1b = (const float*)d_in[4];
    const float* bn1m = (const float*)d_in[5];
    const float* bn1v = (const float*)d_in[6];
    const float* c2w = (const float*)d_in[7];
    const float* c2b = (const float*)d_in[8];
    const float* bn2g = (const float*)d_in[9];
    const float* bn2b = (const float*)d_in[10];
    const float* bn2m = (const float*)d_in[11];
    const float* bn2v = (const float*)d_in[12];
    const float* g1w = (const float*)d_in[13];
    const float* g1as = (const float*)d_in[14];
    const float* g1ad = (const float*)d_in[15];
    const float* g1b = (const float*)d_in[16];
    const float* g2w = (const float*)d_in[17];
    const float* g2as = (const float*)d_in[18];
    const float* g2ad = (const float*)d_in[19];
    const float* g2b = (const float*)d_in[20];
    const float* ow = (const float*)d_in[21];
    const float* ob = (const float*)d_in[22];
    float* out = (float*)d_out;

    // workspace (byte offsets), max ~26.7 MB (< 27.36 MB proven in R4/R5)
    // [0,8M):   h1 fp32 (gemm1..fin1) -> h2 fp32 [0,4M) + pacc2 [4M,8M) (gemm2..fin2)
    // [8M,16M): bufc1 [8M,10M) + x0f [10M,14M) + x0H [14M,16M) (conv..gemm1)
    //           -> pacc1 [8M,16M) (gat1..fin1) -> x2 fp32 [8M,12M) (fin2..end)
    // [16M,24M): x0L [16M,18M) (xprep..gemm1) -> x1H [16M,20M) + x1L [20M,24M) (fin1..gemm2)
    // [24M,..): hT planes, W planes, s/d, pden, part
    char* base = (char*)d_ws;
    float*          h1    = (float*)(base + 0);
    float*          h2    = (float*)(base + 0);
    float*          pacc2 = (float*)(base + 4194304);
    float*          bufc1 = (float*)(base + 8388608);
    float*          x0f   = (float*)(base + 10485760);
    unsigned short* x0H   = (unsigned short*)(base + 14680064);
    unsigned short* x0L   = (unsigned short*)(base + 16777216);
    float*          pacc1 = (float*)(base + 8388608);
    float*          x2    = (float*)(base + 8388608);
    unsigned short* x1H   = (unsigned short*)(base + 16777216);
    unsigned short* x1L   = (unsigned short*)(base + 20971520);
    unsigned short* hTH   = (unsigned short*)(base + 25165824);  // 512 KB
    unsigned short* hTL   = (unsigned short*)(base + 25690112);  // 512 KB
    unsigned short* W1H   = (unsigned short*)(base + 26214400);  // 64 KB each
    unsigned short* W1L   = (unsigned short*)(base + 26279936);
    unsigned short* W2H   = (unsigned short*)(base + 26345472);
    unsigned short* W2L   = (unsigned short*)(base + 26411008);
    float*          s1    = (float*)(base + 26542080);
    float*          d1    = (float*)(base + 26546176);
    float*          s2    = (float*)(base + 26550272);
    float*          d2    = (float*)(base + 26554368);
    float*          pden1 = (float*)(base + 26558464);           // 32 KB
    float*          pden2 = (float*)(base + 26591232);           // 32 KB
    float*          part  = (float*)(base + 26624000);           // 64 KB -> end 26689536

    conv1_pool<<<512, 256, 0, stream>>>(images, c1w, c1b, bn1g, bn1b, bn1m, bn1v, bufc1);
    conv2_fused<<<512, 256, 0, stream>>>(bufc1, c2w, c2b, bn2g, bn2b, bn2m, bn2v, x0f);
    wprep_w<<<256, 256, 0, stream>>>(g1w, g2w, W1H, W1L, W2H, W2L);
    xprep<<<1024, 256, 0, stream>>>(x0f, x0H, x0L);

    gemm_mfma<128, 256, 1><<<dim3(128, 4), 256, 0, stream>>>(x0H, x0L, W1H, W1L, h1, hTH, hTL);
    score_kernel<<<256, 256, 0, stream>>>(h1, g1as, g1ad, s1, d1, 256);
    gat_mfma<256><<<dim3(32, 8), 256, 0, stream>>>(hTH, hTL, s1, d1, pacc1, pden1);
    gat_fin_hl<256, 8, 6><<<2048, 256, 0, stream>>>(pacc1, pden1, h1, g1b, x1H, x1L);

    gemm_mfma<256, 128, 1><<<dim3(128, 2), 256, 0, stream>>>(x1H, x1L, W2H, W2L, h2, hTH, hTL);
    score_kernel<<<256, 256, 0, stream>>>(h2, g2as, g2ad, s2, d2, 128);
    gat_mfma<128><<<dim3(32, 8), 256, 0, stream>>>(hTH, hTL, s2, d2, pacc2, pden2);
    gat_fin_f<128, 8, 5><<<1024, 256, 0, stream>>>(pacc2, pden2, h2, g2b, x2);

    pool_part<<<128, 128, 0, stream>>>(x2, part);
    head_kernel<<<8, 128, 0, stream>>>(part, ow, ob, out);
}